// Round 1
// baseline (324.767 us; speedup 1.0000x reference)
//
#include <hip/hip_runtime.h>
#include <stdint.h>

typedef unsigned short u16;
typedef unsigned int   u32;

typedef float  f32x4  __attribute__((ext_vector_type(4)));
typedef __bf16 bf16x8 __attribute__((ext_vector_type(8)));

// ---------- helpers ----------
__device__ __forceinline__ u16 f2bf(float f) {
  union { float f; u32 u; } c; c.f = f;
  u32 u = c.u + 0x7fffu + ((c.u >> 16) & 1u);   // RNE; inputs finite
  return (u16)(u >> 16);
}
__device__ __forceinline__ float bf2f(u16 h) {
  union { u32 u; float f; } c; c.u = ((u32)h) << 16;
  return c.f;
}
__device__ __forceinline__ void gll16(const void* g, void* l) {
  __builtin_amdgcn_global_load_lds(
      (const __attribute__((address_space(1))) void*)g,
      (__attribute__((address_space(3))) void*)l, 16, 0, 0);
}

// ---------- fp32 -> bf16 pack kernel ----------
__global__ __launch_bounds__(256) void cvt_bf16(const float4* __restrict__ s,
                                                uint2* __restrict__ d, int n4) {
  int i = blockIdx.x * 256 + threadIdx.x;
  if (i >= n4) return;
  float4 v = s[i];
  uint2 o;
  o.x = (u32)f2bf(v.x) | ((u32)f2bf(v.y) << 16);
  o.y = (u32)f2bf(v.z) | ((u32)f2bf(v.w) << 16);
  d[i] = o;
}

// ---------- bf16 NT GEMM: C[M,N] = A[M,K] * B[N,K]^T  (m97 structure) ----------
template <bool OUT_BF16>
__global__ __launch_bounds__(256)
void gemm_nt_bf16(const u16* __restrict__ A, const u16* __restrict__ B,
                  void* __restrict__ Cout, int M, int N, int K) {
  __shared__ u16 As[128 * 32];
  __shared__ u16 Bs[128 * 32];
  const int t    = threadIdx.x;
  const int lane = t & 63;
  const int ml   = lane & 15;
  const int q    = lane >> 4;
  const int wave = t >> 6;
  const int wm   = wave >> 1;
  const int wn   = wave & 1;
  const int m0   = blockIdx.y * 128;
  const int n0   = blockIdx.x * 128;

  f32x4 acc[4][4] = {};

  // staging: 16B chunk c covers tile row c>>2, k-offset (c&3)*8 elements
  const int c1 = t + 256;
  const int r0 = t >> 2,  kk0 = (t & 3) * 8;
  const int r1 = c1 >> 2, kk1 = (c1 & 3) * 8;
  const u16* Ag0 = A + (size_t)(m0 + r0) * K + kk0;
  const u16* Ag1 = A + (size_t)(m0 + r1) * K + kk1;
  const u16* Bg0 = B + (size_t)(n0 + r0) * K + kk0;
  const u16* Bg1 = B + (size_t)(n0 + r1) * K + kk1;
  // wave-uniform LDS bases (HW scatters lane*16)
  u16* AsW0 = As + (size_t)(t & 192) * 8;
  u16* AsW1 = As + (size_t)(256 + (t & 192)) * 8;
  u16* BsW0 = Bs + (size_t)(t & 192) * 8;
  u16* BsW1 = Bs + (size_t)(256 + (t & 192)) * 8;

  for (int k0 = 0; k0 < K; k0 += 32) {
    gll16(Ag0 + k0, AsW0);
    gll16(Ag1 + k0, AsW1);
    gll16(Bg0 + k0, BsW0);
    gll16(Bg1 + k0, BsW1);
    __syncthreads();
    bf16x8 af[4], bfv[4];
#pragma unroll
    for (int i = 0; i < 4; ++i)
      af[i] = *reinterpret_cast<const bf16x8*>(&As[(wm * 64 + i * 16 + ml) * 32 + q * 8]);
#pragma unroll
    for (int i = 0; i < 4; ++i)
      bfv[i] = *reinterpret_cast<const bf16x8*>(&Bs[(wn * 64 + i * 16 + ml) * 32 + q * 8]);
#pragma unroll
    for (int i = 0; i < 4; ++i)
#pragma unroll
      for (int j = 0; j < 4; ++j)
        acc[i][j] = __builtin_amdgcn_mfma_f32_16x16x32_bf16(af[i], bfv[j], acc[i][j], 0, 0, 0);
    __syncthreads();
  }

  // epilogue: C/D frag row = q*4 + reg, col = lane&15 (verified m89/m91)
  const int rowb = m0 + wm * 64 + q * 4;
  const int colb = n0 + wn * 64 + ml;
#pragma unroll
  for (int i = 0; i < 4; ++i)
#pragma unroll
    for (int j = 0; j < 4; ++j)
#pragma unroll
      for (int r = 0; r < 4; ++r) {
        size_t idx = (size_t)(rowb + i * 16 + r) * N + (colb + j * 16);
        float val = acc[i][j][r];
        if (OUT_BF16) ((u16*)Cout)[idx] = f2bf(val);
        else          ((float*)Cout)[idx] = val;
      }
}

// ---------- analytic Gaussian attention as 17-tap conv along L ----------
// taps exp(-d^2/2), d = -8..8
__constant__ float WT[17] = {
  1.2664165549094176e-14f, 2.2897348456652180e-11f, 1.5229979744712628e-08f,
  3.7266531720786709e-06f, 3.3546262790251185e-04f, 1.1108996538242306e-02f,
  1.3533528323661270e-01f, 6.0653065971263342e-01f, 1.0f,
  6.0653065971263342e-01f, 1.3533528323661270e-01f, 1.1108996538242306e-02f,
  3.3546262790251185e-04f, 3.7266531720786709e-06f, 1.5229979744712628e-08f,
  2.2897348456652180e-11f, 1.2664165549094176e-14f
};

__global__ __launch_bounds__(256)
void gauss_conv(const u16* __restrict__ v, u16* __restrict__ att, int L) {
  const int l = blockIdx.x;
  const int b = blockIdx.y;
  const int t = threadIdx.x;
  const int f = t * 4;          // 4 features per thread (1024 / 256)
  const int h = t >> 5;         // head = f >> 7
  // POSITIONS = [center,left,right,first,last,center,left,right]
  int c;
  switch (h) {
    case 0: case 5: c = l;     break;
    case 1: case 6: c = l - 1; break;
    case 2: case 7: c = l + 1; break;
    case 3:         c = 0;     break;
    default:        c = L - 1; break;
  }
  int dlo = (c < 8) ? -c : -8;
  int dhi = (c > L - 9) ? (L - 1 - c) : 8;
  float Z = 0.f;
  for (int d = dlo; d <= dhi; ++d) Z += WT[d + 8];
  float inv = 1.0f / Z;
  float a0 = 0.f, a1 = 0.f, a2 = 0.f, a3 = 0.f;
  const u16* vb = v + (size_t)b * L * 1024 + f;
  for (int d = dlo; d <= dhi; ++d) {
    float w = WT[d + 8];
    uint2 p = *reinterpret_cast<const uint2*>(vb + (size_t)(c + d) * 1024);
    a0 = fmaf(w, bf2f((u16)(p.x & 0xffffu)), a0);
    a1 = fmaf(w, bf2f((u16)(p.x >> 16)),     a1);
    a2 = fmaf(w, bf2f((u16)(p.y & 0xffffu)), a2);
    a3 = fmaf(w, bf2f((u16)(p.y >> 16)),     a3);
  }
  uint2 o;
  o.x = (u32)f2bf(a0 * inv) | ((u32)f2bf(a1 * inv) << 16);
  o.y = (u32)f2bf(a2 * inv) | ((u32)f2bf(a3 * inv) << 16);
  *reinterpret_cast<uint2*>(att + (size_t)(b * L + l) * 1024 + f) = o;
}

// ---------- launch ----------
extern "C" void kernel_launch(void* const* d_in, const int* in_sizes, int n_in,
                              void* d_out, int out_size, void* d_ws, size_t ws_size,
                              hipStream_t stream) {
  const int Bb = 8, L = 2048, E = 1024;
  const int M = Bb * L, N = E, K = E;

  const float* x  = (const float*)d_in[0];
  const float* Wi = (const float*)d_in[1];
  const float* Wo = (const float*)d_in[2];
  float* out = (float*)d_out;

  // ws layout (bf16): [xb 32Mi | v 32Mi | wib 2Mi | wob 2Mi]; att reuses xb
  size_t offV  = (size_t)M * E * 2;
  size_t offWi = offV + (size_t)M * E * 2;
  size_t offWo = offWi + (size_t)E * E * 2;
  size_t need  = offWo + (size_t)E * E * 2;
  if (ws_size < need) return;   // diagnostic: output stays zero

  u16* xb  = (u16*)d_ws;
  u16* v   = (u16*)((char*)d_ws + offV);
  u16* wib = (u16*)((char*)d_ws + offWi);
  u16* wob = (u16*)((char*)d_ws + offWo);
  u16* att = xb;  // safe reuse: conv runs after GEMM1 completes

  int n4x = M * E / 4, n4w = E * E / 4;
  cvt_bf16<<<n4x / 256, 256, 0, stream>>>((const float4*)x,  (uint2*)xb,  n4x);
  cvt_bf16<<<n4w / 256, 256, 0, stream>>>((const float4*)Wi, (uint2*)wib, n4w);
  cvt_bf16<<<n4w / 256, 256, 0, stream>>>((const float4*)Wo, (uint2*)wob, n4w);

  dim3 gg(N / 128, M / 128);
  gemm_nt_bf16<true ><<<gg, 256, 0, stream>>>(xb,  wib, v,   M, N, K);
  gauss_conv<<<dim3(L, Bb), 256, 0, stream>>>(v, att, L);
  gemm_nt_bf16<false><<<gg, 256, 0, stream>>>(att, wob, out, M, N, K);
}

// Round 2
// 262.249 us; speedup vs baseline: 1.2384x; 1.2384x over previous
//
#include <hip/hip_runtime.h>
#include <stdint.h>

typedef unsigned short u16;
typedef unsigned int   u32;

typedef float  f32x4  __attribute__((ext_vector_type(4)));
typedef __bf16 bf16x8 __attribute__((ext_vector_type(8)));

// ---------- helpers ----------
__device__ __forceinline__ u16 f2bf(float f) {
  union { float f; u32 u; } c; c.f = f;
  u32 u = c.u + 0x7fffu + ((c.u >> 16) & 1u);   // RNE; inputs finite
  return (u16)(u >> 16);
}
__device__ __forceinline__ float bf2f(u16 h) {
  union { u32 u; float f; } c; c.u = ((u32)h) << 16;
  return c.f;
}
__device__ __forceinline__ void gll16(const void* g, void* l) {
  __builtin_amdgcn_global_load_lds(
      (const __attribute__((address_space(1))) void*)g,
      (__attribute__((address_space(3))) void*)l, 16, 0, 0);
}

// ---------- fp32 -> bf16 pack kernel ----------
__global__ __launch_bounds__(256) void cvt_bf16(const float4* __restrict__ s,
                                                uint2* __restrict__ d, int n4) {
  int i = blockIdx.x * 256 + threadIdx.x;
  if (i >= n4) return;
  float4 v = s[i];
  uint2 o;
  o.x = (u32)f2bf(v.x) | ((u32)f2bf(v.y) << 16);
  o.y = (u32)f2bf(v.z) | ((u32)f2bf(v.w) << 16);
  d[i] = o;
}

// fused convert for the two weight matrices (blockIdx.y selects which)
__global__ __launch_bounds__(256) void cvt_bf16_w(const float4* __restrict__ s0,
                                                  uint2* __restrict__ d0,
                                                  const float4* __restrict__ s1,
                                                  uint2* __restrict__ d1, int n4) {
  int i = blockIdx.x * 256 + threadIdx.x;
  if (i >= n4) return;
  const float4* s = blockIdx.y ? s1 : s0;
  uint2*        d = blockIdx.y ? d1 : d0;
  float4 v = s[i];
  uint2 o;
  o.x = (u32)f2bf(v.x) | ((u32)f2bf(v.y) << 16);
  o.y = (u32)f2bf(v.z) | ((u32)f2bf(v.w) << 16);
  d[i] = o;
}

// ---------- bf16 NT GEMM: C[M,N] = A[M,K] * B[N,K]^T  (m97 structure) ----------
template <bool OUT_BF16>
__global__ __launch_bounds__(256)
void gemm_nt_bf16(const u16* __restrict__ A, const u16* __restrict__ B,
                  void* __restrict__ Cout, int M, int N, int K) {
  __shared__ u16 As[128 * 32];
  __shared__ u16 Bs[128 * 32];
  const int t    = threadIdx.x;
  const int lane = t & 63;
  const int ml   = lane & 15;
  const int q    = lane >> 4;
  const int wave = t >> 6;
  const int wm   = wave >> 1;
  const int wn   = wave & 1;
  const int m0   = blockIdx.y * 128;
  const int n0   = blockIdx.x * 128;

  f32x4 acc[4][4] = {};

  const int c1 = t + 256;
  const int r0 = t >> 2,  kk0 = (t & 3) * 8;
  const int r1 = c1 >> 2, kk1 = (c1 & 3) * 8;
  const u16* Ag0 = A + (size_t)(m0 + r0) * K + kk0;
  const u16* Ag1 = A + (size_t)(m0 + r1) * K + kk1;
  const u16* Bg0 = B + (size_t)(n0 + r0) * K + kk0;
  const u16* Bg1 = B + (size_t)(n0 + r1) * K + kk1;
  u16* AsW0 = As + (size_t)(t & 192) * 8;
  u16* AsW1 = As + (size_t)(256 + (t & 192)) * 8;
  u16* BsW0 = Bs + (size_t)(t & 192) * 8;
  u16* BsW1 = Bs + (size_t)(256 + (t & 192)) * 8;

  for (int k0 = 0; k0 < K; k0 += 32) {
    gll16(Ag0 + k0, AsW0);
    gll16(Ag1 + k0, AsW1);
    gll16(Bg0 + k0, BsW0);
    gll16(Bg1 + k0, BsW1);
    __syncthreads();
    bf16x8 af[4], bfv[4];
#pragma unroll
    for (int i = 0; i < 4; ++i)
      af[i] = *reinterpret_cast<const bf16x8*>(&As[(wm * 64 + i * 16 + ml) * 32 + q * 8]);
#pragma unroll
    for (int i = 0; i < 4; ++i)
      bfv[i] = *reinterpret_cast<const bf16x8*>(&Bs[(wn * 64 + i * 16 + ml) * 32 + q * 8]);
#pragma unroll
    for (int i = 0; i < 4; ++i)
#pragma unroll
      for (int j = 0; j < 4; ++j)
        acc[i][j] = __builtin_amdgcn_mfma_f32_16x16x32_bf16(af[i], bfv[j], acc[i][j], 0, 0, 0);
    __syncthreads();
  }

  const int rowb = m0 + wm * 64 + q * 4;
  const int colb = n0 + wn * 64 + ml;
#pragma unroll
  for (int i = 0; i < 4; ++i)
#pragma unroll
    for (int j = 0; j < 4; ++j)
#pragma unroll
      for (int r = 0; r < 4; ++r) {
        size_t idx = (size_t)(rowb + i * 16 + r) * N + (colb + j * 16);
        float val = acc[i][j][r];
        if (OUT_BF16) ((u16*)Cout)[idx] = f2bf(val);
        else          ((float*)Cout)[idx] = val;
      }
}

// ---------- analytic Gaussian attention: 13-tap conv along L ----------
// Head is BLOCK-uniform; 13 taps fully unrolled with immediate weights;
// boundary via clamp + select-zero weight (no divergent loop bounds).
// Truncation at |d|<=6 drops relative mass 7.5e-6 (out err ~1e-5, << bf16 ulp).
__global__ __launch_bounds__(256)
void gauss_conv(const u16* __restrict__ v, u16* __restrict__ att, int L) {
  constexpr float wt[13] = {
    1.5229979744712628e-08f, 3.7266531720786709e-06f, 3.3546262790251185e-04f,
    1.1108996538242306e-02f, 1.3533528323661270e-01f, 6.0653065971263342e-01f,
    1.0f,
    6.0653065971263342e-01f, 1.3533528323661270e-01f, 1.1108996538242306e-02f,
    3.3546262790251185e-04f, 3.7266531720786709e-06f, 1.5229979744712628e-08f
  };
  const int t  = threadIdx.x;
  const int fg = t & 15;                 // 16 feature-groups of 8 features
  const int li = t >> 4;                 // 16 query positions per block
  const int l  = blockIdx.x * 16 + li;
  const int h  = blockIdx.y;             // head: block-uniform
  const int b  = blockIdx.z;
  // POSITIONS = [center,left,right,first,last,center,left,right]
  int c;
  switch (h) {
    case 0: case 5: c = l;     break;
    case 1: case 6: c = l - 1; break;
    case 2: case 7: c = l + 1; break;
    case 3:         c = 0;     break;
    default:        c = L - 1; break;
  }
  const int fbase = h * 128 + fg * 8;
  const u16* vb = v + (size_t)b * L * 1024 + fbase;

  float a[8] = {};
  float Z = 0.f;
#pragma unroll
  for (int d = -6; d <= 6; ++d) {
    int idx = c + d;
    bool ok = (idx >= 0) && (idx < L);
    int ic = idx < 0 ? 0 : (idx >= L ? L - 1 : idx);
    float w = ok ? wt[d + 6] : 0.f;
    Z += w;
    uint4 p = *reinterpret_cast<const uint4*>(vb + (size_t)ic * 1024);
    a[0] = fmaf(w, bf2f((u16)(p.x & 0xffffu)), a[0]);
    a[1] = fmaf(w, bf2f((u16)(p.x >> 16)),     a[1]);
    a[2] = fmaf(w, bf2f((u16)(p.y & 0xffffu)), a[2]);
    a[3] = fmaf(w, bf2f((u16)(p.y >> 16)),     a[3]);
    a[4] = fmaf(w, bf2f((u16)(p.z & 0xffffu)), a[4]);
    a[5] = fmaf(w, bf2f((u16)(p.z >> 16)),     a[5]);
    a[6] = fmaf(w, bf2f((u16)(p.w & 0xffffu)), a[6]);
    a[7] = fmaf(w, bf2f((u16)(p.w >> 16)),     a[7]);
  }
  float inv = 1.0f / Z;
  uint4 o;
  o.x = (u32)f2bf(a[0] * inv) | ((u32)f2bf(a[1] * inv) << 16);
  o.y = (u32)f2bf(a[2] * inv) | ((u32)f2bf(a[3] * inv) << 16);
  o.z = (u32)f2bf(a[4] * inv) | ((u32)f2bf(a[5] * inv) << 16);
  o.w = (u32)f2bf(a[6] * inv) | ((u32)f2bf(a[7] * inv) << 16);
  *reinterpret_cast<uint4*>(att + (size_t)(b * L + l) * 1024 + fbase) = o;
}

// ---------- launch ----------
extern "C" void kernel_launch(void* const* d_in, const int* in_sizes, int n_in,
                              void* d_out, int out_size, void* d_ws, size_t ws_size,
                              hipStream_t stream) {
  const int Bb = 8, L = 2048, E = 1024;
  const int M = Bb * L, N = E, K = E;

  const float* x  = (const float*)d_in[0];
  const float* Wi = (const float*)d_in[1];
  const float* Wo = (const float*)d_in[2];
  float* out = (float*)d_out;

  size_t offV  = (size_t)M * E * 2;
  size_t offWi = offV + (size_t)M * E * 2;
  size_t offWo = offWi + (size_t)E * E * 2;
  size_t need  = offWo + (size_t)E * E * 2;
  if (ws_size < need) return;

  u16* xb  = (u16*)d_ws;
  u16* v   = (u16*)((char*)d_ws + offV);
  u16* wib = (u16*)((char*)d_ws + offWi);
  u16* wob = (u16*)((char*)d_ws + offWo);
  u16* att = xb;  // reuse: conv runs after GEMM1 completes

  int n4x = M * E / 4, n4w = E * E / 4;
  cvt_bf16<<<n4x / 256, 256, 0, stream>>>((const float4*)x, (uint2*)xb, n4x);
  cvt_bf16_w<<<dim3(n4w / 256, 2), 256, 0, stream>>>(
      (const float4*)Wi, (uint2*)wib, (const float4*)Wo, (uint2*)wob, n4w);

  dim3 gg(N / 128, M / 128);
  gemm_nt_bf16<true ><<<gg, 256, 0, stream>>>(xb,  wib, v,   M, N, K);
  gauss_conv<<<dim3(L / 16, 8, Bb), 256, 0, stream>>>(v, att, L);
  gemm_nt_bf16<false><<<gg, 256, 0, stream>>>(att, wob, out, M, N, K);
}

// Round 3
// 221.944 us; speedup vs baseline: 1.4633x; 1.1816x over previous
//
#include <hip/hip_runtime.h>
#include <stdint.h>

typedef unsigned short u16;
typedef unsigned int   u32;

typedef float  f32x4  __attribute__((ext_vector_type(4)));
typedef __bf16 bf16x8 __attribute__((ext_vector_type(8)));

// ---------- helpers ----------
__device__ __forceinline__ u16 f2bf(float f) {
  union { float f; u32 u; } c; c.f = f;
  u32 u = c.u + 0x7fffu + ((c.u >> 16) & 1u);   // RNE; inputs finite
  return (u16)(u >> 16);
}
__device__ __forceinline__ float bf2f(u16 h) {
  union { u32 u; float f; } c; c.u = ((u32)h) << 16;
  return c.f;
}
__device__ __forceinline__ void gll16(const void* g, void* l) {
  __builtin_amdgcn_global_load_lds(
      (const __attribute__((address_space(1))) void*)g,
      (__attribute__((address_space(3))) void*)l, 16, 0, 0);
}

// ---------- fp32 -> bf16 pack kernel ----------
__global__ __launch_bounds__(256) void cvt_bf16(const float4* __restrict__ s,
                                                uint2* __restrict__ d, int n4) {
  int i = blockIdx.x * 256 + threadIdx.x;
  if (i >= n4) return;
  float4 v = s[i];
  uint2 o;
  o.x = (u32)f2bf(v.x) | ((u32)f2bf(v.y) << 16);
  o.y = (u32)f2bf(v.z) | ((u32)f2bf(v.w) << 16);
  d[i] = o;
}

// fused convert for the two weight matrices (blockIdx.y selects which)
__global__ __launch_bounds__(256) void cvt_bf16_w(const float4* __restrict__ s0,
                                                  uint2* __restrict__ d0,
                                                  const float4* __restrict__ s1,
                                                  uint2* __restrict__ d1, int n4) {
  int i = blockIdx.x * 256 + threadIdx.x;
  if (i >= n4) return;
  const float4* s = blockIdx.y ? s1 : s0;
  uint2*        d = blockIdx.y ? d1 : d0;
  float4 v = s[i];
  uint2 o;
  o.x = (u32)f2bf(v.x) | ((u32)f2bf(v.y) << 16);
  o.y = (u32)f2bf(v.z) | ((u32)f2bf(v.w) << 16);
  d[i] = o;
}

// ---------- bf16 NT GEMM: C[M,N] = A[M,K] * B[N,K]^T  (m97 structure) ----------
// Grid MUST be (8, M/128). XCD swizzle: linear id & 7 picks an XCD-band of
// 16 m-tiles; within a band, n varies fastest so the band's A-tiles
// (16 x 32 KB = 512 KB) + all of B (2 MB) stay resident in that XCD's 4 MB L2.
// __launch_bounds__(256,4): cap arch VGPRs so 4 blocks/CU fit -> all 1024
// blocks resident in one round (no tail).
template <bool OUT_BF16>
__global__ __launch_bounds__(256, 4)
void gemm_nt_bf16(const u16* __restrict__ A, const u16* __restrict__ B,
                  void* __restrict__ Cout, int M, int N, int K) {
  __shared__ u16 As[128 * 32];
  __shared__ u16 Bs[128 * 32];
  const int t    = threadIdx.x;
  const int lane = t & 63;
  const int ml   = lane & 15;
  const int q    = lane >> 4;
  const int wave = t >> 6;
  const int wm   = wave >> 1;
  const int wn   = wave & 1;

  // ---- XCD-locality swizzle (bijection on [0, ntiles*mtiles)) ----
  const int flat    = blockIdx.y * 8 + blockIdx.x;   // gridDim.x == 8
  const int xcd     = flat & 7;
  const int slot    = flat >> 3;                     // [0, mtiles)
  const int per_xcd = gridDim.y >> 3;                // mtiles / 8 (= 16)
  const int mt      = xcd * per_xcd + (slot >> 3);
  const int nt      = slot & 7;
  const int m0      = mt * 128;
  const int n0      = nt * 128;

  f32x4 acc[4][4] = {};

  const int c1 = t + 256;
  const int r0 = t >> 2,  kk0 = (t & 3) * 8;
  const int r1 = c1 >> 2, kk1 = (c1 & 3) * 8;
  const u16* Ag0 = A + (size_t)(m0 + r0) * K + kk0;
  const u16* Ag1 = A + (size_t)(m0 + r1) * K + kk1;
  const u16* Bg0 = B + (size_t)(n0 + r0) * K + kk0;
  const u16* Bg1 = B + (size_t)(n0 + r1) * K + kk1;
  u16* AsW0 = As + (size_t)(t & 192) * 8;
  u16* AsW1 = As + (size_t)(256 + (t & 192)) * 8;
  u16* BsW0 = Bs + (size_t)(t & 192) * 8;
  u16* BsW1 = Bs + (size_t)(256 + (t & 192)) * 8;

  for (int k0 = 0; k0 < K; k0 += 32) {
    gll16(Ag0 + k0, AsW0);
    gll16(Ag1 + k0, AsW1);
    gll16(Bg0 + k0, BsW0);
    gll16(Bg1 + k0, BsW1);
    __syncthreads();
    bf16x8 af[4], bfv[4];
#pragma unroll
    for (int i = 0; i < 4; ++i)
      af[i] = *reinterpret_cast<const bf16x8*>(&As[(wm * 64 + i * 16 + ml) * 32 + q * 8]);
#pragma unroll
    for (int i = 0; i < 4; ++i)
      bfv[i] = *reinterpret_cast<const bf16x8*>(&Bs[(wn * 64 + i * 16 + ml) * 32 + q * 8]);
#pragma unroll
    for (int i = 0; i < 4; ++i)
#pragma unroll
      for (int j = 0; j < 4; ++j)
        acc[i][j] = __builtin_amdgcn_mfma_f32_16x16x32_bf16(af[i], bfv[j], acc[i][j], 0, 0, 0);
    __syncthreads();
  }

  const int rowb = m0 + wm * 64 + q * 4;
  const int colb = n0 + wn * 64 + ml;
#pragma unroll
  for (int i = 0; i < 4; ++i)
#pragma unroll
    for (int j = 0; j < 4; ++j)
#pragma unroll
      for (int r = 0; r < 4; ++r) {
        size_t idx = (size_t)(rowb + i * 16 + r) * N + (colb + j * 16);
        float val = acc[i][j][r];
        if (OUT_BF16) ((u16*)Cout)[idx] = f2bf(val);
        else          ((float*)Cout)[idx] = val;
      }
}

// ---------- analytic Gaussian attention: 13-tap conv along L ----------
__global__ __launch_bounds__(256)
void gauss_conv(const u16* __restrict__ v, u16* __restrict__ att, int L) {
  constexpr float wt[13] = {
    1.5229979744712628e-08f, 3.7266531720786709e-06f, 3.3546262790251185e-04f,
    1.1108996538242306e-02f, 1.3533528323661270e-01f, 6.0653065971263342e-01f,
    1.0f,
    6.0653065971263342e-01f, 1.3533528323661270e-01f, 1.1108996538242306e-02f,
    3.3546262790251185e-04f, 3.7266531720786709e-06f, 1.5229979744712628e-08f
  };
  const int t  = threadIdx.x;
  const int fg = t & 15;                 // 16 feature-groups of 8 features
  const int li = t >> 4;                 // 16 query positions per block
  const int l  = blockIdx.x * 16 + li;
  const int h  = blockIdx.y;             // head: block-uniform
  const int b  = blockIdx.z;
  // POSITIONS = [center,left,right,first,last,center,left,right]
  int c;
  switch (h) {
    case 0: case 5: c = l;     break;
    case 1: case 6: c = l - 1; break;
    case 2: case 7: c = l + 1; break;
    case 3:         c = 0;     break;
    default:        c = L - 1; break;
  }
  const int fbase = h * 128 + fg * 8;
  const u16* vb = v + (size_t)b * L * 1024 + fbase;

  float a[8] = {};
  float Z = 0.f;
#pragma unroll
  for (int d = -6; d <= 6; ++d) {
    int idx = c + d;
    bool ok = (idx >= 0) && (idx < L);
    int ic = idx < 0 ? 0 : (idx >= L ? L - 1 : idx);
    float w = ok ? wt[d + 6] : 0.f;
    Z += w;
    uint4 p = *reinterpret_cast<const uint4*>(vb + (size_t)ic * 1024);
    a[0] = fmaf(w, bf2f((u16)(p.x & 0xffffu)), a[0]);
    a[1] = fmaf(w, bf2f((u16)(p.x >> 16)),     a[1]);
    a[2] = fmaf(w, bf2f((u16)(p.y & 0xffffu)), a[2]);
    a[3] = fmaf(w, bf2f((u16)(p.y >> 16)),     a[3]);
    a[4] = fmaf(w, bf2f((u16)(p.z & 0xffffu)), a[4]);
    a[5] = fmaf(w, bf2f((u16)(p.z >> 16)),     a[5]);
    a[6] = fmaf(w, bf2f((u16)(p.w & 0xffffu)), a[6]);
    a[7] = fmaf(w, bf2f((u16)(p.w >> 16)),     a[7]);
  }
  float inv = 1.0f / Z;
  uint4 o;
  o.x = (u32)f2bf(a[0] * inv) | ((u32)f2bf(a[1] * inv) << 16);
  o.y = (u32)f2bf(a[2] * inv) | ((u32)f2bf(a[3] * inv) << 16);
  o.z = (u32)f2bf(a[4] * inv) | ((u32)f2bf(a[5] * inv) << 16);
  o.w = (u32)f2bf(a[6] * inv) | ((u32)f2bf(a[7] * inv) << 16);
  *reinterpret_cast<uint4*>(att + (size_t)(b * L + l) * 1024 + fbase) = o;
}

// ---------- launch ----------
extern "C" void kernel_launch(void* const* d_in, const int* in_sizes, int n_in,
                              void* d_out, int out_size, void* d_ws, size_t ws_size,
                              hipStream_t stream) {
  const int Bb = 8, L = 2048, E = 1024;
  const int M = Bb * L, N = E, K = E;

  const float* x  = (const float*)d_in[0];
  const float* Wi = (const float*)d_in[1];
  const float* Wo = (const float*)d_in[2];
  float* out = (float*)d_out;

  size_t offV  = (size_t)M * E * 2;
  size_t offWi = offV + (size_t)M * E * 2;
  size_t offWo = offWi + (size_t)E * E * 2;
  size_t need  = offWo + (size_t)E * E * 2;
  if (ws_size < need) return;

  u16* xb  = (u16*)d_ws;
  u16* v   = (u16*)((char*)d_ws + offV);
  u16* wib = (u16*)((char*)d_ws + offWi);
  u16* wob = (u16*)((char*)d_ws + offWo);
  u16* att = xb;  // reuse: conv runs after GEMM1 completes

  int n4x = M * E / 4, n4w = E * E / 4;
  cvt_bf16<<<n4x / 256, 256, 0, stream>>>((const float4*)x, (uint2*)xb, n4x);
  cvt_bf16_w<<<dim3(n4w / 256, 2), 256, 0, stream>>>(
      (const float4*)Wi, (uint2*)wib, (const float4*)Wo, (uint2*)wob, n4w);

  dim3 gg(N / 128, M / 128);   // (8, 128) — swizzle in-kernel assumes x==8
  gemm_nt_bf16<true ><<<gg, 256, 0, stream>>>(xb,  wib, v,   M, N, K);
  gauss_conv<<<dim3(L / 16, 8, Bb), 256, 0, stream>>>(v, att, L);
  gemm_nt_bf16<false><<<gg, 256, 0, stream>>>(att, wob, out, M, N, K);
}